// Round 2
// baseline (156.790 us; speedup 1.0000x reference)
//
#include <hip/hip_runtime.h>
#include <stdint.h>

#define NROWS 2048
#define DDIM  9216
#define T64   32                      // max 64-row tiles per dim (2048/64)
#define NTRI  528                     // T64*(T64+1)/2 triangle tiles
#define WKLEN 2304                    // DDIM/4 : K-range per wave
#define BK    32                      // K-step per stage
#define WKIT  72                      // WKLEN/BK : K iterations per wave

typedef unsigned short u16;
typedef __bf16 bf16x8 __attribute__((ext_vector_type(8)));
typedef float  f32x4  __attribute__((ext_vector_type(4)));

// ws layout: [0] int cnt, [4] float sq, [256..) u16 nf[2048][9216] (37.75 MB)
#define NF_OFF 256

__device__ __forceinline__ u16 f2bf(float f) {
    uint32_t x = __float_as_uint(f);
    x += 0x7fffu + ((x >> 16) & 1u);          // round-to-nearest-even
    return (u16)(x >> 16);
}

__device__ __forceinline__ void gload16(const u16* g, u16* l) {
    __builtin_amdgcn_global_load_lds(
        (const __attribute__((address_space(1))) uint32_t*)g,
        (__attribute__((address_space(3))) uint32_t*)l, 16, 0, 0);
}

// ---------------- kernel 1: per-row stats + normalize + compact ----------------
__global__ __launch_bounds__(256) void stats_kernel(const float* __restrict__ wgt,
                                                    const float* __restrict__ mask,
                                                    u16* __restrict__ nf,
                                                    int* __restrict__ cnt) {
    int n = blockIdx.x;
    if (mask[n] == 0.0f) return;              // inactive filter: skip entirely
    int tid = threadIdx.x;
    const float4* row = (const float4*)(wgt + (size_t)n * DDIM);
    float4 v[9];
    float s = 0.f, ss = 0.f;
#pragma unroll
    for (int i = 0; i < 9; ++i) {
        v[i] = row[tid + 256 * i];
        s  += v[i].x + v[i].y + v[i].z + v[i].w;
        ss += v[i].x * v[i].x + v[i].y * v[i].y + v[i].z * v[i].z + v[i].w * v[i].w;
    }
#pragma unroll
    for (int o = 32; o > 0; o >>= 1) { s += __shfl_down(s, o); ss += __shfl_down(ss, o); }
    __shared__ float rs[4], rss[4];
    __shared__ float smean, sinv;
    __shared__ int   sidx;
    int w = tid >> 6, l = tid & 63;
    if (l == 0) { rs[w] = s; rss[w] = ss; }
    __syncthreads();
    if (tid == 0) {
        float S  = rs[0] + rs[1] + rs[2] + rs[3];
        float SS = rss[0] + rss[1] + rss[2] + rss[3];
        float mean = S / (float)DDIM;
        float var  = SS / (float)DDIM - mean * mean;
        float sd   = sqrtf(fmaxf(var, 0.f));
        if (sd == 0.f) sd = 1.f;              // reference: std==0 -> 1
        smean = mean; sinv = 1.f / sd;
        sidx = atomicAdd(cnt, 1);             // compacted slot (order irrelevant)
    }
    __syncthreads();
    float mean = smean, inv = sinv;
    u16* dst = nf + (size_t)sidx * DDIM;
#pragma unroll
    for (int i = 0; i < 9; ++i) {
        int e = (tid + 256 * i) * 4;
        uint32_t lo = (uint32_t)f2bf((v[i].x - mean) * inv) |
                      ((uint32_t)f2bf((v[i].y - mean) * inv) << 16);
        uint32_t hi = (uint32_t)f2bf((v[i].z - mean) * inv) |
                      ((uint32_t)f2bf((v[i].w - mean) * inv) << 16);
        uint2 u; u.x = lo; u.y = hi;
        *(uint2*)(dst + e) = u;
    }
}

// ---------------- kernel 2: fused 64x64-tile GEMM + square-reduce ----------------
// Block = 4 waves, each owning a PRIVATE K-quarter with PRIVATE quad-buffered
// LDS (4 x (A 4KB + B 4KB) per wave = 128 KB/block). No __syncthreads in the
// K-loop. 4-deep pipeline: 3 stages in flight (24 loads), counted vmcnt(24)
// (diag 12) per iteration -> ~540 cy of latency tolerance vs the ~500 cy L3
// round trip. Never drains vmcnt to 0 until the last 3 iterations.
// BK=32 row-major [64][32] u16 is NATURALLY bank-conflict-free: row stride is
// 64 B = 16 banks, quad q reads 16-B chunk q of rows m16 (parity alternates
// the bank half) -> exactly 8 dwords/bank across the wave. No swizzle needed.
template<bool DIAG, int AHEAD>
__device__ __forceinline__ void kstep(const u16* pA, const u16* pB, int it,
                                      u16* Ac, u16* An, u16* Bc, u16* Bn,
                                      int m16, int quad, f32x4 acc[4][4]) {
    if (AHEAD == 3) {                         // steady state: issue stage it+3
        const u16* a = pA + (it + 3) * BK;
#pragma unroll
        for (int i = 0; i < 4; ++i) gload16(a + i * 16 * DDIM, An + i * 512);
        if (!DIAG) {
            const u16* b = pB + (it + 3) * BK;
#pragma unroll
            for (int i = 0; i < 4; ++i) gload16(b + i * 16 * DDIM, Bn + i * 512);
        }
    }
    // wait until stage(it) is resident; AHEAD later stages may stay in flight.
    // encodings: vmcnt[3:0]=bits0-3, vmcnt[5:4]=bits14-15, exp=7, lgkm=15.
    if (DIAG) {
        if      (AHEAD == 3) __builtin_amdgcn_s_waitcnt(0x0F7C); // vmcnt(12)
        else if (AHEAD == 2) __builtin_amdgcn_s_waitcnt(0x0F78); // vmcnt(8)
        else if (AHEAD == 1) __builtin_amdgcn_s_waitcnt(0x0F74); // vmcnt(4)
        else                 __builtin_amdgcn_s_waitcnt(0x0F70); // vmcnt(0)
    } else {
        if      (AHEAD == 3) __builtin_amdgcn_s_waitcnt(0x4F78); // vmcnt(24)
        else if (AHEAD == 2) __builtin_amdgcn_s_waitcnt(0x4F70); // vmcnt(16)
        else if (AHEAD == 1) __builtin_amdgcn_s_waitcnt(0x0F78); // vmcnt(8)
        else                 __builtin_amdgcn_s_waitcnt(0x0F70); // vmcnt(0)
    }
    __builtin_amdgcn_wave_barrier();
    const u16* rB = DIAG ? Ac : Bc;
    bf16x8 af[4], bfr[4];
#pragma unroll
    for (int fm = 0; fm < 4; ++fm)
        af[fm] = *(const bf16x8*)&Ac[(fm * 16 + m16) * BK + quad * 8];
#pragma unroll
    for (int fn = 0; fn < 4; ++fn)
        bfr[fn] = *(const bf16x8*)&rB[(fn * 16 + m16) * BK + quad * 8];
#pragma unroll
    for (int fm = 0; fm < 4; ++fm)
#pragma unroll
        for (int fn = 0; fn < 4; ++fn)
            acc[fm][fn] = __builtin_amdgcn_mfma_f32_16x16x32_bf16(
                af[fm], bfr[fn], acc[fm][fn], 0, 0, 0);
    __builtin_amdgcn_wave_barrier();          // keep next stage's DMA after reads
}

template<bool DIAG>
__device__ __forceinline__ void kloop(const u16* pA, const u16* pB,
                                      u16* base, int m16, int quad,
                                      f32x4 acc[4][4]) {
    u16* A0 = base;            u16* A1 = base + 2048;
    u16* A2 = base + 4096;     u16* A3 = base + 6144;
    u16* B0 = base + 8192;     u16* B1 = base + 10240;
    u16* B2 = base + 12288;    u16* B3 = base + 14336;
    // prologue: issue stages 0,1,2
#pragma unroll
    for (int s = 0; s < 3; ++s) {
        const u16* a = pA + s * BK;
        u16* Ad = base + s * 2048;
#pragma unroll
        for (int i = 0; i < 4; ++i) gload16(a + i * 16 * DDIM, Ad + i * 512);
        if (!DIAG) {
            const u16* b = pB + s * BK;
            u16* Bd = base + 8192 + s * 2048;
#pragma unroll
            for (int i = 0; i < 4; ++i) gload16(b + i * 16 * DDIM, Bd + i * 512);
        }
    }
    // steady state: it = 0..67 (17 groups of 4), each issues it+3 (<= 70)
    for (int it = 0; it < WKIT - 4; it += 4) {
        kstep<DIAG, 3>(pA, pB, it,     A0, A3, B0, B3, m16, quad, acc);
        kstep<DIAG, 3>(pA, pB, it + 1, A1, A0, B1, B0, m16, quad, acc);
        kstep<DIAG, 3>(pA, pB, it + 2, A2, A1, B2, B1, m16, quad, acc);
        kstep<DIAG, 3>(pA, pB, it + 3, A3, A2, B3, B2, m16, quad, acc);
    }
    // tail: it = 68 issues stage 71, then drain 2,1,0
    kstep<DIAG, 3>(pA, pB, WKIT - 4, A0, A3, B0, B3, m16, quad, acc);
    kstep<DIAG, 2>(pA, pB, WKIT - 3, A1, A0, B1, B0, m16, quad, acc);
    kstep<DIAG, 1>(pA, pB, WKIT - 2, A2, A1, B2, B1, m16, quad, acc);
    kstep<DIAG, 0>(pA, pB, WKIT - 1, A3, A2, B3, B2, m16, quad, acc);
}

__global__ __launch_bounds__(256) void gemm_kernel(const u16* __restrict__ nf,
                                                   const int* __restrict__ cnt,
                                                   float* __restrict__ sq) {
    __shared__ u16 ls[65536];                 // 128 KB: 4 waves x 4 x (A 4KB + B 4KB)
    int A = *cnt;
    int nt = (A + 63) >> 6;
    int t = blockIdx.x, bi = 0, len = T64;
    while (t >= len) { t -= len; --len; ++bi; }
    int bj = bi + t;
    if (bj >= nt) return;                     // bi <= bj
    int r0 = bi << 6, c0 = bj << 6;
    int tid = threadIdx.x, l = tid & 63, w = tid >> 6;
    int quad = l >> 4, m16 = l & 15;
    int kbeg = w * WKLEN;
    // staging lane map: lane l covers row (l>>2) + i*16, col chunk (l&3)*8.
    const u16* pA = nf + (size_t)(r0 + (l >> 2)) * DDIM + ((l & 3) << 3) + kbeg;
    const u16* pB = nf + (size_t)(c0 + (l >> 2)) * DDIM + ((l & 3) << 3) + kbeg;
    u16* base = ls + w * 16384;               // 32 KB per wave
    f32x4 acc[4][4] = {};
    if (bi == bj) kloop<true >(pA, pB, base, m16, quad, acc);
    else          kloop<false>(pA, pB, base, m16, quad, acc);

    // ---- epilogue: park partials in own wave's LDS region (frag-major) ----
    float* fw = (float*)ls + w * 8192;        // own 32 KB region base; use 16 KB
#pragma unroll
    for (int fm = 0; fm < 4; ++fm)
#pragma unroll
        for (int fn = 0; fn < 4; ++fn)
            *(f32x4*)&fw[(fm * 4 + fn) * 256 + l * 4] = acc[fm][fn];
    __syncthreads();
    const float* fs = (const float*)ls;
    float local = 0.f;
#pragma unroll
    for (int i = 0; i < 4; ++i) {
        int o = tid * 4 + i * 1024;           // offset within a parked 16 KB block
        f32x4 v = *(const f32x4*)&fs[o];
        v += *(const f32x4*)&fs[o + 8192];    // wave regions are 8192 floats apart
        v += *(const f32x4*)&fs[o + 16384];
        v += *(const f32x4*)&fs[o + 24576];
        int f = o >> 8, lk = (o >> 2) & 63;   // frag id, lane id; o&3 = reg r
        int row = ((f >> 2) << 4) + ((lk >> 4) << 2);   // + r
        int col = ((f & 3) << 4) + (lk & 15);
        int gj = c0 + col;
        if (gj < A) {
#pragma unroll
            for (int r = 0; r < 4; ++r) {
                int gi = r0 + row + r;
                if (gi < gj) local += v[r] * v[r];
            }
        }
    }
#pragma unroll
    for (int o = 32; o > 0; o >>= 1) local += __shfl_down(local, o);
    if (l == 0) atomicAdd(sq, local);         // 4 atomics per active block
}

// ---------------- kernel 3: finalize ----------------
__global__ void final_kernel(const int* __restrict__ cnt, const float* __restrict__ sq,
                             float* __restrict__ out) {
    long long A = *cnt;
    long long na = A * (A - 1) / 2;           // sum of strict-upper mask products
    double loss = 0.0;
    if (na > 0) loss = (double)(*sq) / ((double)DDIM * (double)DDIM) / (double)na;
    out[0] = (float)loss;
}

extern "C" void kernel_launch(void* const* d_in, const int* in_sizes, int n_in,
                              void* d_out, int out_size, void* d_ws, size_t ws_size,
                              hipStream_t stream) {
    (void)in_sizes; (void)n_in; (void)out_size; (void)ws_size;
    const float* wgt  = (const float*)d_in[0];
    const float* mask = (const float*)d_in[1];
    float* out = (float*)d_out;
    char*  ws  = (char*)d_ws;

    int*   cnt = (int*)ws;
    float* sq  = (float*)(ws + 4);
    u16*   nf  = (u16*)(ws + NF_OFF);

    hipMemsetAsync(ws, 0, 256, stream);
    stats_kernel<<<NROWS, 256, 0, stream>>>(wgt, mask, nf, cnt);
    gemm_kernel<<<NTRI, 256, 0, stream>>>(nf, cnt, sq);
    final_kernel<<<1, 1, 0, stream>>>(cnt, sq, out);
}

// Round 3
// 146.687 us; speedup vs baseline: 1.0689x; 1.0689x over previous
//
#include <hip/hip_runtime.h>
#include <stdint.h>

#define NROWS 2048
#define DDIM  9216
#define T128  16                      // max 128-row tiles per dim (2048/128)
#define NT128 136                     // T128*(T128+1)/2 triangle tiles
#define KS    8                       // K-slices (one per XCD)
#define KSLEN 1152                    // DDIM/KS
#define BK    64                      // K-step per stage
#define KIT   18                      // KSLEN/BK

typedef unsigned short u16;
typedef __bf16 bf16x8 __attribute__((ext_vector_type(8)));
typedef float  f32x4  __attribute__((ext_vector_type(4)));

// ws layout: [0] int cnt, [4] float sq,
//            [256..) u16 nf[2048][9216]                      (37.75 MB)
//            [P_OFF..) float P[136][8][4][4096] partials     (71.3 MB max)
#define NF_OFF 256
#define P_OFF  37748992ull            // NF_OFF + 2048*9216*2 (16B aligned)

__device__ __forceinline__ u16 f2bf(float f) {
    uint32_t x = __float_as_uint(f);
    x += 0x7fffu + ((x >> 16) & 1u);          // round-to-nearest-even
    return (u16)(x >> 16);
}

__device__ __forceinline__ void gload16(const u16* g, u16* l) {
    __builtin_amdgcn_global_load_lds(
        (const __attribute__((address_space(1))) uint32_t*)g,
        (__attribute__((address_space(3))) uint32_t*)l, 16, 0, 0);
}

// ---------------- kernel 1: per-row stats + normalize + compact ----------------
__global__ __launch_bounds__(256) void stats_kernel(const float* __restrict__ wgt,
                                                    const float* __restrict__ mask,
                                                    u16* __restrict__ nf,
                                                    int* __restrict__ cnt) {
    int n = blockIdx.x;
    if (mask[n] == 0.0f) return;              // inactive filter: skip entirely
    int tid = threadIdx.x;
    const float4* row = (const float4*)(wgt + (size_t)n * DDIM);
    float4 v[9];
    float s = 0.f, ss = 0.f;
#pragma unroll
    for (int i = 0; i < 9; ++i) {
        v[i] = row[tid + 256 * i];
        s  += v[i].x + v[i].y + v[i].z + v[i].w;
        ss += v[i].x * v[i].x + v[i].y * v[i].y + v[i].z * v[i].z + v[i].w * v[i].w;
    }
#pragma unroll
    for (int o = 32; o > 0; o >>= 1) { s += __shfl_down(s, o); ss += __shfl_down(ss, o); }
    __shared__ float rs[4], rss[4];
    __shared__ float smean, sinv;
    __shared__ int   sidx;
    int w = tid >> 6, l = tid & 63;
    if (l == 0) { rs[w] = s; rss[w] = ss; }
    __syncthreads();
    if (tid == 0) {
        float S  = rs[0] + rs[1] + rs[2] + rs[3];
        float SS = rss[0] + rss[1] + rss[2] + rss[3];
        float mean = S / (float)DDIM;
        float var  = SS / (float)DDIM - mean * mean;
        float sd   = sqrtf(fmaxf(var, 0.f));
        if (sd == 0.f) sd = 1.f;              // reference: std==0 -> 1
        smean = mean; sinv = 1.f / sd;
        sidx = atomicAdd(cnt, 1);             // compacted slot (order irrelevant)
    }
    __syncthreads();
    float mean = smean, inv = sinv;
    u16* dst = nf + (size_t)sidx * DDIM;
#pragma unroll
    for (int i = 0; i < 9; ++i) {
        int e = (tid + 256 * i) * 4;
        uint32_t lo = (uint32_t)f2bf((v[i].x - mean) * inv) |
                      ((uint32_t)f2bf((v[i].y - mean) * inv) << 16);
        uint32_t hi = (uint32_t)f2bf((v[i].z - mean) * inv) |
                      ((uint32_t)f2bf((v[i].w - mean) * inv) << 16);
        uint2 u; u.x = lo; u.y = hi;
        *(uint2*)(dst + e) = u;
    }
}

// ---------------- kernel 2a: 128x128-tile partial GEMM, K-split by 8 ----------------
// Grid = 136 tiles x 8 kslices; bid = t*8 + k, so round-robin dispatch puts
// every block of kslice k on XCD k -> each XCD re-reads only its own
// 1024x1152 bf16 slab (2.36 MB, L2-resident). 4 waves, each owns a 64x64
// output quadrant. Shared double-buffered LDS tile (A 16KB + B 16KB) x2 =
// 64 KB/block -> 2 blocks/CU for TLP. Raw s_barrier + per-wave counted
// vmcnt(8) keeps the next stage's DMA in flight across the barrier.
// XOR swizzle (verified R1): global source col chunk (l&7)^(l>>3), ds_read
// chunk (quad^(row&7)) ^ (kk<<2) -> bank-conflict-free ds_read_b128.
template<bool DIAG>
__device__ __forceinline__ void stage(const u16* pA, const u16* pB, int kt,
                                      u16* Ab, u16* Bb, int w) {
    const u16* a = pA + kt * BK;
#pragma unroll
    for (int i = 0; i < 4; ++i)
        gload16(a + (size_t)(8 * i) * DDIM, Ab + w * 2048 + i * 512);
    if (!DIAG) {
        const u16* b = pB + kt * BK;
#pragma unroll
        for (int i = 0; i < 4; ++i)
            gload16(b + (size_t)(8 * i) * DDIM, Bb + w * 2048 + i * 512);
    }
}

template<bool DIAG>
__device__ __forceinline__ void compute(const u16* Ab, const u16* Bb,
                                        int wr, int wc, int m16, int quad,
                                        f32x4 acc[4][4]) {
    const u16* rB = DIAG ? Ab : Bb;
#pragma unroll
    for (int kk = 0; kk < 2; ++kk) {
        int sw = ((quad ^ (m16 & 7)) << 3) ^ (kk << 5);
        bf16x8 af[4], bfr[4];
#pragma unroll
        for (int fm = 0; fm < 4; ++fm)
            af[fm] = *(const bf16x8*)&Ab[(wr * 64 + fm * 16 + m16) * 64 + sw];
#pragma unroll
        for (int fn = 0; fn < 4; ++fn)
            bfr[fn] = *(const bf16x8*)&rB[(wc * 64 + fn * 16 + m16) * 64 + sw];
#pragma unroll
        for (int fm = 0; fm < 4; ++fm)
#pragma unroll
            for (int fn = 0; fn < 4; ++fn)
                acc[fm][fn] = __builtin_amdgcn_mfma_f32_16x16x32_bf16(
                    af[fm], bfr[fn], acc[fm][fn], 0, 0, 0);
    }
}

__device__ __forceinline__ void barrier_fenced() {
    asm volatile("" ::: "memory");
    __builtin_amdgcn_s_barrier();
    asm volatile("" ::: "memory");
}

template<bool DIAG>
__device__ __forceinline__ void kloop(const u16* pA, const u16* pB, u16* ls,
                                      int w, int wr, int wc, int m16, int quad,
                                      f32x4 acc[4][4]) {
    u16* A0 = ls;          u16* B0 = ls + 8192;
    u16* A1 = ls + 16384;  u16* B1 = ls + 24576;
    bool dead = DIAG && (w == 2);             // sub-diagonal quadrant: all masked
    stage<DIAG>(pA, pB, 0, A0, B0, w);
    for (int kt = 0; kt < KIT; kt += 2) {
        // -- even step: compute buf0, prefetch kt+1 into buf1 --
        stage<DIAG>(pA, pB, kt + 1, A1, B1, w);
        __builtin_amdgcn_s_waitcnt(DIAG ? 0x0F74 : 0x0F78);  // vmcnt(4)/vmcnt(8)
        barrier_fenced();                     // all waves' stage kt resident
        if (!dead) compute<DIAG>(A0, B0, wr, wc, m16, quad, acc);
        barrier_fenced();                     // all waves done reading buf0
        // -- odd step: compute buf1, prefetch kt+2 into buf0 --
        if (kt + 2 < KIT) {
            stage<DIAG>(pA, pB, kt + 2, A0, B0, w);
            __builtin_amdgcn_s_waitcnt(DIAG ? 0x0F74 : 0x0F78);
        } else {
            __builtin_amdgcn_s_waitcnt(0x0F70);               // drain at end
        }
        barrier_fenced();
        if (!dead) compute<DIAG>(A1, B1, wr, wc, m16, quad, acc);
        barrier_fenced();
    }
}

__global__ __launch_bounds__(256) void gemm_kernel(const u16* __restrict__ nf,
                                                   const int* __restrict__ cnt,
                                                   float* __restrict__ P) {
    __shared__ u16 ls[32768];                 // 64 KB: 2 x (A 16KB + B 16KB)
    int A = *cnt;
    int bid = blockIdx.x;
    int t = bid >> 3, k = bid & 7;            // k = bid%8 -> XCD k (round-robin)
    int tt = t, bi = 0, len = T128;
    while (tt >= len) { tt -= len; --len; ++bi; }
    int bj = bi + tt;                         // bi <= bj
    int r0 = bi << 7, c0 = bj << 7;
    if (c0 >= A) return;
    int tid = threadIdx.x, l = tid & 63, w = tid >> 6;
    int quad = l >> 4, m16 = l & 15;
    int wr = w >> 1, wc = w & 1;
    int colsw = ((l & 7) ^ (l >> 3)) << 3;    // pre-swizzled global col chunk
    size_t kbase = (size_t)k * KSLEN + colsw;
    const u16* pA = nf + (size_t)(r0 + 32 * w + (l >> 3)) * DDIM + kbase;
    const u16* pB = nf + (size_t)(c0 + 32 * w + (l >> 3)) * DDIM + kbase;
    f32x4 acc[4][4] = {};
    if (bi == bj) kloop<true >(pA, pB, ls, w, wr, wc, m16, quad, acc);
    else          kloop<false>(pA, pB, ls, w, wr, wc, m16, quad, acc);
    // frag-major coalesced partial store: P[(t*8+k)*4 + w][frag][lane][reg]
    float* dst = P + ((size_t)(t * 8 + k) * 4 + w) * 4096;
#pragma unroll
    for (int fm = 0; fm < 4; ++fm)
#pragma unroll
        for (int fn = 0; fn < 4; ++fn)
            *(f32x4*)&dst[(fm * 4 + fn) * 256 + l * 4] = acc[fm][fn];
}

// ---------------- kernel 2b: reduce 8 k-partials, square, mask, sum ----------------
__global__ __launch_bounds__(256) void reduce_kernel(const float* __restrict__ P,
                                                     const int* __restrict__ cnt,
                                                     float* __restrict__ sq) {
    int A = *cnt;
    int t = blockIdx.x;
    int tt = t, bi = 0, len = T128;
    while (tt >= len) { tt -= len; --len; ++bi; }
    int bj = bi + tt;
    int r0 = bi << 7, c0 = bj << 7;
    if (c0 >= A) return;
    int tid = threadIdx.x, l = tid & 63;
    const float* base = P + (size_t)t * 131072;   // 8 kslices x 16384 floats
    float local = 0.f;
#pragma unroll
    for (int m = 0; m < 16; ++m) {
        int v = tid + 256 * m;                // vector index in [0,4096)
        const float* p0 = base + (size_t)v * 4;
        f32x4 s = *(const f32x4*)p0;
#pragma unroll
        for (int k = 1; k < 8; ++k) s += *(const f32x4*)(p0 + (size_t)k * 16384);
        int w = v >> 10, f = (v >> 6) & 15, ln = v & 63;
        int i = ((w >> 1) << 6) + ((f >> 2) << 4) + ((ln >> 4) << 2);
        int j = ((w & 1) << 6) + ((f & 3) << 4) + (ln & 15);
        int gj = c0 + j;
        if (gj < A) {
#pragma unroll
            for (int r = 0; r < 4; ++r) {
                int gi = r0 + i + r;
                if (gi < gj) local += s[r] * s[r];
            }
        }
    }
#pragma unroll
    for (int o = 32; o > 0; o >>= 1) local += __shfl_down(local, o);
    if (l == 0) atomicAdd(sq, local);         // 4 atomics per active block
}

// ---------------- kernel 3: finalize ----------------
__global__ void final_kernel(const int* __restrict__ cnt, const float* __restrict__ sq,
                             float* __restrict__ out) {
    long long A = *cnt;
    long long na = A * (A - 1) / 2;           // sum of strict-upper mask products
    double loss = 0.0;
    if (na > 0) loss = (double)(*sq) / ((double)DDIM * (double)DDIM) / (double)na;
    out[0] = (float)loss;
}

extern "C" void kernel_launch(void* const* d_in, const int* in_sizes, int n_in,
                              void* d_out, int out_size, void* d_ws, size_t ws_size,
                              hipStream_t stream) {
    (void)in_sizes; (void)n_in; (void)out_size; (void)ws_size;
    const float* wgt  = (const float*)d_in[0];
    const float* mask = (const float*)d_in[1];
    float* out = (float*)d_out;
    char*  ws  = (char*)d_ws;

    int*   cnt = (int*)ws;
    float* sq  = (float*)(ws + 4);
    u16*   nf  = (u16*)(ws + NF_OFF);
    float* P   = (float*)(ws + P_OFF);

    hipMemsetAsync(ws, 0, 256, stream);
    stats_kernel<<<NROWS, 256, 0, stream>>>(wgt, mask, nf, cnt);
    gemm_kernel<<<NT128 * KS, 256, 0, stream>>>(nf, cnt, P);
    reduce_kernel<<<NT128, 256, 0, stream>>>(P, cnt, sq);
    final_kernel<<<1, 1, 0, stream>>>(cnt, sq, out);
}

// Round 4
// 144.381 us; speedup vs baseline: 1.0859x; 1.0160x over previous
//
#include <hip/hip_runtime.h>
#include <stdint.h>

#define NROWS 2048
#define DDIM  9216
#define T128  16                      // max 128-row tiles per dim (2048/128)
#define NT128 136                     // T128*(T128+1)/2 triangle tiles
#define KS    8                       // K-slices (one per XCD)
#define KSLEN 1152                    // DDIM/KS
#define BK    64                      // K-step per stage
#define KIT   18                      // KSLEN/BK

typedef unsigned short u16;
typedef __bf16 bf16x8 __attribute__((ext_vector_type(8)));
typedef float  f32x4  __attribute__((ext_vector_type(4)));

// ws layout: [0] int cnt, [4] float sq,
//            [256..) u16 nf[2048][9216]                      (37.75 MB)
//            [P_OFF..) float P[136][8][4][4096] partials     (71.3 MB max)
#define NF_OFF 256
#define P_OFF  37748992ull            // NF_OFF + 2048*9216*2 (16B aligned)

__device__ __forceinline__ u16 f2bf(float f) {
    uint32_t x = __float_as_uint(f);
    x += 0x7fffu + ((x >> 16) & 1u);          // round-to-nearest-even
    return (u16)(x >> 16);
}

__device__ __forceinline__ void gload16(const u16* g, u16* l) {
    __builtin_amdgcn_global_load_lds(
        (const __attribute__((address_space(1))) uint32_t*)g,
        (__attribute__((address_space(3))) uint32_t*)l, 16, 0, 0);
}

// ---------------- kernel 1: per-row stats + normalize + compact ----------------
__global__ __launch_bounds__(256) void stats_kernel(const float* __restrict__ wgt,
                                                    const float* __restrict__ mask,
                                                    u16* __restrict__ nf,
                                                    int* __restrict__ cnt) {
    int n = blockIdx.x;
    if (mask[n] == 0.0f) return;              // inactive filter: skip entirely
    int tid = threadIdx.x;
    const float4* row = (const float4*)(wgt + (size_t)n * DDIM);
    float4 v[9];
    float s = 0.f, ss = 0.f;
#pragma unroll
    for (int i = 0; i < 9; ++i) {
        v[i] = row[tid + 256 * i];
        s  += v[i].x + v[i].y + v[i].z + v[i].w;
        ss += v[i].x * v[i].x + v[i].y * v[i].y + v[i].z * v[i].z + v[i].w * v[i].w;
    }
#pragma unroll
    for (int o = 32; o > 0; o >>= 1) { s += __shfl_down(s, o); ss += __shfl_down(ss, o); }
    __shared__ float rs[4], rss[4];
    __shared__ float smean, sinv;
    __shared__ int   sidx;
    int w = tid >> 6, l = tid & 63;
    if (l == 0) { rs[w] = s; rss[w] = ss; }
    __syncthreads();
    if (tid == 0) {
        float S  = rs[0] + rs[1] + rs[2] + rs[3];
        float SS = rss[0] + rss[1] + rss[2] + rss[3];
        float mean = S / (float)DDIM;
        float var  = SS / (float)DDIM - mean * mean;
        float sd   = sqrtf(fmaxf(var, 0.f));
        if (sd == 0.f) sd = 1.f;              // reference: std==0 -> 1
        smean = mean; sinv = 1.f / sd;
        sidx = atomicAdd(cnt, 1);             // compacted slot (order irrelevant)
    }
    __syncthreads();
    float mean = smean, inv = sinv;
    u16* dst = nf + (size_t)sidx * DDIM;
#pragma unroll
    for (int i = 0; i < 9; ++i) {
        int e = (tid + 256 * i) * 4;
        uint32_t lo = (uint32_t)f2bf((v[i].x - mean) * inv) |
                      ((uint32_t)f2bf((v[i].y - mean) * inv) << 16);
        uint32_t hi = (uint32_t)f2bf((v[i].z - mean) * inv) |
                      ((uint32_t)f2bf((v[i].w - mean) * inv) << 16);
        uint2 u; u.x = lo; u.y = hi;
        *(uint2*)(dst + e) = u;
    }
}

// ---------------- kernel 2a: 128x128-tile partial GEMM, K-split by 8 ----------------
// Triangle is enumerated over nt = ceil(A/128) (NOT T128), so active blocks
// occupy a CONTIGUOUS grid prefix bid = 0..8*ntri-1. With 288 active blocks
// <= 512-slot initial dispatch, the CP's round-robin places every block of
// kslice k (= bid&7) on XCD k BEFORE any dead-block backfill can scramble the
// binding -> each XCD re-reads only its own 1024x1152 slab (2.36 MB,
// L2-resident). 4 waves, each owns a 64x64 output quadrant. Shared
// double-buffered LDS (A 16KB + B 16KB) x2 = 64 KB -> 2 blocks/CU for TLP.
// Counted vmcnt keeps next stage's DMA in flight across the barrier; setprio
// wraps the MFMA cluster (T5).
template<bool DIAG>
__device__ __forceinline__ void stage(const u16* pA, const u16* pB, int kt,
                                      u16* Ab, u16* Bb, int w) {
    const u16* a = pA + kt * BK;
#pragma unroll
    for (int i = 0; i < 4; ++i)
        gload16(a + (size_t)(8 * i) * DDIM, Ab + w * 2048 + i * 512);
    if (!DIAG) {
        const u16* b = pB + kt * BK;
#pragma unroll
        for (int i = 0; i < 4; ++i)
            gload16(b + (size_t)(8 * i) * DDIM, Bb + w * 2048 + i * 512);
    }
}

template<bool DIAG>
__device__ __forceinline__ void compute(const u16* Ab, const u16* Bb,
                                        int wr, int wc, int m16, int quad,
                                        f32x4 acc[4][4]) {
    const u16* rB = DIAG ? Ab : Bb;
#pragma unroll
    for (int kk = 0; kk < 2; ++kk) {
        int sw = ((quad ^ (m16 & 7)) << 3) ^ (kk << 5);
        bf16x8 af[4], bfr[4];
#pragma unroll
        for (int fm = 0; fm < 4; ++fm)
            af[fm] = *(const bf16x8*)&Ab[(wr * 64 + fm * 16 + m16) * 64 + sw];
#pragma unroll
        for (int fn = 0; fn < 4; ++fn)
            bfr[fn] = *(const bf16x8*)&rB[(wc * 64 + fn * 16 + m16) * 64 + sw];
        __builtin_amdgcn_s_setprio(1);
#pragma unroll
        for (int fm = 0; fm < 4; ++fm)
#pragma unroll
            for (int fn = 0; fn < 4; ++fn)
                acc[fm][fn] = __builtin_amdgcn_mfma_f32_16x16x32_bf16(
                    af[fm], bfr[fn], acc[fm][fn], 0, 0, 0);
        __builtin_amdgcn_s_setprio(0);
    }
}

__device__ __forceinline__ void barrier_fenced() {
    asm volatile("" ::: "memory");
    __builtin_amdgcn_s_barrier();
    asm volatile("" ::: "memory");
}

template<bool DIAG>
__device__ __forceinline__ void kloop(const u16* pA, const u16* pB, u16* ls,
                                      int w, int wr, int wc, int m16, int quad,
                                      f32x4 acc[4][4]) {
    u16* A0 = ls;          u16* B0 = ls + 8192;
    u16* A1 = ls + 16384;  u16* B1 = ls + 24576;
    bool dead = DIAG && (w == 2);             // sub-diagonal quadrant: all masked
    stage<DIAG>(pA, pB, 0, A0, B0, w);
    for (int kt = 0; kt < KIT; kt += 2) {
        // -- even step: compute buf0, prefetch kt+1 into buf1 --
        stage<DIAG>(pA, pB, kt + 1, A1, B1, w);
        __builtin_amdgcn_s_waitcnt(DIAG ? 0x0F74 : 0x0F78);  // vmcnt(4)/vmcnt(8)
        barrier_fenced();                     // all waves' stage kt resident
        if (!dead) compute<DIAG>(A0, B0, wr, wc, m16, quad, acc);
        barrier_fenced();                     // all waves done reading buf0
        // -- odd step: compute buf1, prefetch kt+2 into buf0 --
        if (kt + 2 < KIT) {
            stage<DIAG>(pA, pB, kt + 2, A0, B0, w);
            __builtin_amdgcn_s_waitcnt(DIAG ? 0x0F74 : 0x0F78);
        } else {
            __builtin_amdgcn_s_waitcnt(0x0F70);               // drain at end
        }
        barrier_fenced();
        if (!dead) compute<DIAG>(A1, B1, wr, wc, m16, quad, acc);
        barrier_fenced();
    }
}

__global__ __launch_bounds__(256) void gemm_kernel(const u16* __restrict__ nf,
                                                   const int* __restrict__ cnt,
                                                   float* __restrict__ P) {
    __shared__ u16 ls[32768];                 // 64 KB: 2 x (A 16KB + B 16KB)
    int A = *cnt;
    int nt = (A + 127) >> 7;                  // active 128-tiles per dim
    int ntri = nt * (nt + 1) >> 1;
    int bid = blockIdx.x;
    int t = bid >> 3, k = bid & 7;            // k = bid%8 -> XCD k (round-robin)
    if (t >= ntri) return;                    // contiguous active prefix
    int tt = t, bi = 0, len = nt;             // nt-triangle enumeration
    while (tt >= len) { tt -= len; --len; ++bi; }
    int bj = bi + tt;                         // bi <= bj
    int r0 = bi << 7, c0 = bj << 7;
    int tid = threadIdx.x, l = tid & 63, w = tid >> 6;
    int quad = l >> 4, m16 = l & 15;
    int wr = w >> 1, wc = w & 1;
    int colsw = ((l & 7) ^ (l >> 3)) << 3;    // pre-swizzled global col chunk
    size_t kbase = (size_t)k * KSLEN + colsw;
    const u16* pA = nf + (size_t)(r0 + 32 * w + (l >> 3)) * DDIM + kbase;
    const u16* pB = nf + (size_t)(c0 + 32 * w + (l >> 3)) * DDIM + kbase;
    f32x4 acc[4][4] = {};
    if (bi == bj) kloop<true >(pA, pB, ls, w, wr, wc, m16, quad, acc);
    else          kloop<false>(pA, pB, ls, w, wr, wc, m16, quad, acc);
    // frag-major coalesced partial store: P[(t*8+k)*4 + w][frag][lane][reg]
    float* dst = P + ((size_t)(t * 8 + k) * 4 + w) * 4096;
#pragma unroll
    for (int fm = 0; fm < 4; ++fm)
#pragma unroll
        for (int fn = 0; fn < 4; ++fn)
            *(f32x4*)&dst[(fm * 4 + fn) * 256 + l * 4] = acc[fm][fn];
}

// ---------------- kernel 2b: reduce 8 k-partials, square, mask, sum ----------------
__global__ __launch_bounds__(256) void reduce_kernel(const float* __restrict__ P,
                                                     const int* __restrict__ cnt,
                                                     float* __restrict__ sq) {
    int A = *cnt;
    int nt = (A + 127) >> 7;
    int ntri = nt * (nt + 1) >> 1;
    int t = blockIdx.x;
    if (t >= ntri) return;
    int tt = t, bi = 0, len = nt;             // SAME nt-triangle mapping as gemm
    while (tt >= len) { tt -= len; --len; ++bi; }
    int bj = bi + tt;
    int r0 = bi << 7, c0 = bj << 7;
    int tid = threadIdx.x, l = tid & 63;
    const float* base = P + (size_t)t * 131072;   // 8 kslices x 16384 floats
    float local = 0.f;
#pragma unroll
    for (int m = 0; m < 16; ++m) {
        int v = tid + 256 * m;                // vector index in [0,4096)
        const float* p0 = base + (size_t)v * 4;
        f32x4 s = *(const f32x4*)p0;
#pragma unroll
        for (int k = 1; k < 8; ++k) s += *(const f32x4*)(p0 + (size_t)k * 16384);
        int w = v >> 10, f = (v >> 6) & 15, ln = v & 63;
        int i = ((w >> 1) << 6) + ((f >> 2) << 4) + ((ln >> 4) << 2);
        int j = ((w & 1) << 6) + ((f & 3) << 4) + (ln & 15);
        int gj = c0 + j;
        if (gj < A) {
#pragma unroll
            for (int r = 0; r < 4; ++r) {
                int gi = r0 + i + r;
                if (gi < gj) local += s[r] * s[r];
            }
        }
    }
#pragma unroll
    for (int o = 32; o > 0; o >>= 1) local += __shfl_down(local, o);
    if (l == 0) atomicAdd(sq, local);         // 4 atomics per active block
}

// ---------------- kernel 3: finalize ----------------
__global__ void final_kernel(const int* __restrict__ cnt, const float* __restrict__ sq,
                             float* __restrict__ out) {
    long long A = *cnt;
    long long na = A * (A - 1) / 2;           // sum of strict-upper mask products
    double loss = 0.0;
    if (na > 0) loss = (double)(*sq) / ((double)DDIM * (double)DDIM) / (double)na;
    out[0] = (float)loss;
}

extern "C" void kernel_launch(void* const* d_in, const int* in_sizes, int n_in,
                              void* d_out, int out_size, void* d_ws, size_t ws_size,
                              hipStream_t stream) {
    (void)in_sizes; (void)n_in; (void)out_size; (void)ws_size;
    const float* wgt  = (const float*)d_in[0];
    const float* mask = (const float*)d_in[1];
    float* out = (float*)d_out;
    char*  ws  = (char*)d_ws;

    int*   cnt = (int*)ws;
    float* sq  = (float*)(ws + 4);
    u16*   nf  = (u16*)(ws + NF_OFF);
    float* P   = (float*)(ws + P_OFF);

    hipMemsetAsync(ws, 0, 256, stream);
    stats_kernel<<<NROWS, 256, 0, stream>>>(wgt, mask, nf, cnt);
    gemm_kernel<<<NT128 * KS, 256, 0, stream>>>(nf, cnt, P);
    reduce_kernel<<<NT128, 256, 0, stream>>>(P, cnt, sq);
    final_kernel<<<1, 1, 0, stream>>>(cnt, sq, out);
}

// Round 5
// 143.940 us; speedup vs baseline: 1.0893x; 1.0031x over previous
//
#include <hip/hip_runtime.h>
#include <stdint.h>

#define NROWS 2048
#define DDIM  9216
#define T128  16                      // max 128-row tiles per dim (2048/128)
#define NT128 136                     // T128*(T128+1)/2 triangle tiles
#define KS    8                       // K-slices (one per XCD)
#define KSLEN 1152                    // DDIM/KS
#define BK    64                      // K-step per stage
#define KIT   18                      // KSLEN/BK

typedef unsigned short u16;
typedef __bf16 bf16x8 __attribute__((ext_vector_type(8)));
typedef float  f32x4  __attribute__((ext_vector_type(4)));

// ws layout: [0] int cnt, [4] float sq,
//            [256..) u16 nf[2048][9216]                      (37.75 MB)
//            [P_OFF..) float P[136][8][4][4096] partials     (71.3 MB max)
#define NF_OFF 256
#define P_OFF  37748992ull            // NF_OFF + 2048*9216*2 (16B aligned)

__device__ __forceinline__ u16 f2bf(float f) {
    uint32_t x = __float_as_uint(f);
    x += 0x7fffu + ((x >> 16) & 1u);          // round-to-nearest-even
    return (u16)(x >> 16);
}

__device__ __forceinline__ void gload16(const u16* g, u16* l) {
    __builtin_amdgcn_global_load_lds(
        (const __attribute__((address_space(1))) uint32_t*)g,
        (__attribute__((address_space(3))) uint32_t*)l, 16, 0, 0);
}

// ---------------- kernel 1: per-row stats + normalize + compact ----------------
__global__ __launch_bounds__(256) void stats_kernel(const float* __restrict__ wgt,
                                                    const float* __restrict__ mask,
                                                    u16* __restrict__ nf,
                                                    int* __restrict__ cnt) {
    int n = blockIdx.x;
    if (mask[n] == 0.0f) return;              // inactive filter: skip entirely
    int tid = threadIdx.x;
    const float4* row = (const float4*)(wgt + (size_t)n * DDIM);
    float4 v[9];
    float s = 0.f, ss = 0.f;
#pragma unroll
    for (int i = 0; i < 9; ++i) {
        v[i] = row[tid + 256 * i];
        s  += v[i].x + v[i].y + v[i].z + v[i].w;
        ss += v[i].x * v[i].x + v[i].y * v[i].y + v[i].z * v[i].z + v[i].w * v[i].w;
    }
#pragma unroll
    for (int o = 32; o > 0; o >>= 1) { s += __shfl_down(s, o); ss += __shfl_down(ss, o); }
    __shared__ float rs[4], rss[4];
    __shared__ float smean, sinv;
    __shared__ int   sidx;
    int w = tid >> 6, l = tid & 63;
    if (l == 0) { rs[w] = s; rss[w] = ss; }
    __syncthreads();
    if (tid == 0) {
        float S  = rs[0] + rs[1] + rs[2] + rs[3];
        float SS = rss[0] + rss[1] + rss[2] + rss[3];
        float mean = S / (float)DDIM;
        float var  = SS / (float)DDIM - mean * mean;
        float sd   = sqrtf(fmaxf(var, 0.f));
        if (sd == 0.f) sd = 1.f;              // reference: std==0 -> 1
        smean = mean; sinv = 1.f / sd;
        sidx = atomicAdd(cnt, 1);             // compacted slot (order irrelevant)
    }
    __syncthreads();
    float mean = smean, inv = sinv;
    u16* dst = nf + (size_t)sidx * DDIM;
#pragma unroll
    for (int i = 0; i < 9; ++i) {
        int e = (tid + 256 * i) * 4;
        uint32_t lo = (uint32_t)f2bf((v[i].x - mean) * inv) |
                      ((uint32_t)f2bf((v[i].y - mean) * inv) << 16);
        uint32_t hi = (uint32_t)f2bf((v[i].z - mean) * inv) |
                      ((uint32_t)f2bf((v[i].w - mean) * inv) << 16);
        uint2 u; u.x = lo; u.y = hi;
        *(uint2*)(dst + e) = u;
    }
}

// ---------------- kernel 2a: 128x128-tile partial GEMM, K-split by 8 ----------------
// (unchanged from R4 for clean attribution of the reduce fix)
template<bool DIAG>
__device__ __forceinline__ void stage(const u16* pA, const u16* pB, int kt,
                                      u16* Ab, u16* Bb, int w) {
    const u16* a = pA + kt * BK;
#pragma unroll
    for (int i = 0; i < 4; ++i)
        gload16(a + (size_t)(8 * i) * DDIM, Ab + w * 2048 + i * 512);
    if (!DIAG) {
        const u16* b = pB + kt * BK;
#pragma unroll
        for (int i = 0; i < 4; ++i)
            gload16(b + (size_t)(8 * i) * DDIM, Bb + w * 2048 + i * 512);
    }
}

template<bool DIAG>
__device__ __forceinline__ void compute(const u16* Ab, const u16* Bb,
                                        int wr, int wc, int m16, int quad,
                                        f32x4 acc[4][4]) {
    const u16* rB = DIAG ? Ab : Bb;
#pragma unroll
    for (int kk = 0; kk < 2; ++kk) {
        int sw = ((quad ^ (m16 & 7)) << 3) ^ (kk << 5);
        bf16x8 af[4], bfr[4];
#pragma unroll
        for (int fm = 0; fm < 4; ++fm)
            af[fm] = *(const bf16x8*)&Ab[(wr * 64 + fm * 16 + m16) * 64 + sw];
#pragma unroll
        for (int fn = 0; fn < 4; ++fn)
            bfr[fn] = *(const bf16x8*)&rB[(wc * 64 + fn * 16 + m16) * 64 + sw];
        __builtin_amdgcn_s_setprio(1);
#pragma unroll
        for (int fm = 0; fm < 4; ++fm)
#pragma unroll
            for (int fn = 0; fn < 4; ++fn)
                acc[fm][fn] = __builtin_amdgcn_mfma_f32_16x16x32_bf16(
                    af[fm], bfr[fn], acc[fm][fn], 0, 0, 0);
        __builtin_amdgcn_s_setprio(0);
    }
}

__device__ __forceinline__ void barrier_fenced() {
    asm volatile("" ::: "memory");
    __builtin_amdgcn_s_barrier();
    asm volatile("" ::: "memory");
}

template<bool DIAG>
__device__ __forceinline__ void kloop(const u16* pA, const u16* pB, u16* ls,
                                      int w, int wr, int wc, int m16, int quad,
                                      f32x4 acc[4][4]) {
    u16* A0 = ls;          u16* B0 = ls + 8192;
    u16* A1 = ls + 16384;  u16* B1 = ls + 24576;
    bool dead = DIAG && (w == 2);             // sub-diagonal quadrant: all masked
    stage<DIAG>(pA, pB, 0, A0, B0, w);
    for (int kt = 0; kt < KIT; kt += 2) {
        // -- even step: compute buf0, prefetch kt+1 into buf1 --
        stage<DIAG>(pA, pB, kt + 1, A1, B1, w);
        __builtin_amdgcn_s_waitcnt(DIAG ? 0x0F74 : 0x0F78);  // vmcnt(4)/vmcnt(8)
        barrier_fenced();                     // all waves' stage kt resident
        if (!dead) compute<DIAG>(A0, B0, wr, wc, m16, quad, acc);
        barrier_fenced();                     // all waves done reading buf0
        // -- odd step: compute buf1, prefetch kt+2 into buf0 --
        if (kt + 2 < KIT) {
            stage<DIAG>(pA, pB, kt + 2, A0, B0, w);
            __builtin_amdgcn_s_waitcnt(DIAG ? 0x0F74 : 0x0F78);
        } else {
            __builtin_amdgcn_s_waitcnt(0x0F70);               // drain at end
        }
        barrier_fenced();
        if (!dead) compute<DIAG>(A1, B1, wr, wc, m16, quad, acc);
        barrier_fenced();
    }
}

__global__ __launch_bounds__(256) void gemm_kernel(const u16* __restrict__ nf,
                                                   const int* __restrict__ cnt,
                                                   float* __restrict__ P) {
    __shared__ u16 ls[32768];                 // 64 KB: 2 x (A 16KB + B 16KB)
    int A = *cnt;
    int nt = (A + 127) >> 7;                  // active 128-tiles per dim
    int ntri = nt * (nt + 1) >> 1;
    int bid = blockIdx.x;
    int t = bid >> 3, k = bid & 7;            // k = bid%8 -> XCD k (round-robin)
    if (t >= ntri) return;                    // contiguous active prefix
    int tt = t, bi = 0, len = nt;             // nt-triangle enumeration
    while (tt >= len) { tt -= len; --len; ++bi; }
    int bj = bi + tt;                         // bi <= bj
    int r0 = bi << 7, c0 = bj << 7;
    int tid = threadIdx.x, l = tid & 63, w = tid >> 6;
    int quad = l >> 4, m16 = l & 15;
    int wr = w >> 1, wc = w & 1;
    int colsw = ((l & 7) ^ (l >> 3)) << 3;    // pre-swizzled global col chunk
    size_t kbase = (size_t)k * KSLEN + colsw;
    const u16* pA = nf + (size_t)(r0 + 32 * w + (l >> 3)) * DDIM + kbase;
    const u16* pB = nf + (size_t)(c0 + 32 * w + (l >> 3)) * DDIM + kbase;
    f32x4 acc[4][4] = {};
    if (bi == bj) kloop<true >(pA, pB, ls, w, wr, wc, m16, quad, acc);
    else          kloop<false>(pA, pB, ls, w, wr, wc, m16, quad, acc);
    // frag-major coalesced partial store: P[(t*8+k)*4 + w][frag][lane][reg]
    float* dst = P + ((size_t)(t * 8 + k) * 4 + w) * 4096;
#pragma unroll
    for (int fm = 0; fm < 4; ++fm)
#pragma unroll
        for (int fn = 0; fn < 4; ++fn)
            *(f32x4*)&dst[(fm * 4 + fn) * 256 + l * 4] = acc[fm][fn];
}

// ---------------- kernel 2b: reduce 8 k-partials, square, mask, sum ----------------
// R5: 4 blocks per tile (grid = NT128*4), each handles a 1024-vec chunk.
// Per k-iteration the whole block reads a CONTIGUOUS 16-KB span of one
// kslice's partial (perfectly coalesced), 8 loads in flight per thread ->
// BW-bound (~3-4 us) instead of the R4 version's 36-block latency-bound
// cross-XCD gather (est. 15-25 us).
__global__ __launch_bounds__(256) void reduce_kernel(const float* __restrict__ P,
                                                     const int* __restrict__ cnt,
                                                     float* __restrict__ sq) {
    int A = *cnt;
    int nt = (A + 127) >> 7;
    int ntri = nt * (nt + 1) >> 1;
    int t = blockIdx.x >> 2, c = blockIdx.x & 3;
    if (t >= ntri) return;
    int tt = t, bi = 0, len = nt;             // SAME nt-triangle mapping as gemm
    while (tt >= len) { tt -= len; --len; ++bi; }
    int bj = bi + tt;
    int r0 = bi << 7, c0 = bj << 7;
    int tid = threadIdx.x, l = tid & 63;
    const float* base = P + (size_t)t * 131072;   // 8 kslices x 16384 floats
    float local = 0.f;
#pragma unroll
    for (int mm = 0; mm < 4; ++mm) {
        int v = (c << 10) + (mm << 8) + tid;  // vector index in [c*1024, c*1024+1024)
        const float* p0 = base + (size_t)v * 4;
        f32x4 s = *(const f32x4*)p0;
#pragma unroll
        for (int k = 1; k < 8; ++k) s += *(const f32x4*)(p0 + (size_t)k * 16384);
        int w = v >> 10, f = (v >> 6) & 15, ln = v & 63;
        int i = ((w >> 1) << 6) + ((f >> 2) << 4) + ((ln >> 4) << 2);
        int j = ((w & 1) << 6) + ((f & 3) << 4) + (ln & 15);
        int gj = c0 + j;
        if (gj < A) {
#pragma unroll
            for (int r = 0; r < 4; ++r) {
                int gi = r0 + i + r;
                if (gi < gj) local += s[r] * s[r];
            }
        }
    }
#pragma unroll
    for (int o = 32; o > 0; o >>= 1) local += __shfl_down(local, o);
    if (l == 0) atomicAdd(sq, local);         // 4 atomics per active block
}

// ---------------- kernel 3: finalize ----------------
__global__ void final_kernel(const int* __restrict__ cnt, const float* __restrict__ sq,
                             float* __restrict__ out) {
    long long A = *cnt;
    long long na = A * (A - 1) / 2;           // sum of strict-upper mask products
    double loss = 0.0;
    if (na > 0) loss = (double)(*sq) / ((double)DDIM * (double)DDIM) / (double)na;
    out[0] = (float)loss;
}

extern "C" void kernel_launch(void* const* d_in, const int* in_sizes, int n_in,
                              void* d_out, int out_size, void* d_ws, size_t ws_size,
                              hipStream_t stream) {
    (void)in_sizes; (void)n_in; (void)out_size; (void)ws_size;
    const float* wgt  = (const float*)d_in[0];
    const float* mask = (const float*)d_in[1];
    float* out = (float*)d_out;
    char*  ws  = (char*)d_ws;

    int*   cnt = (int*)ws;
    float* sq  = (float*)(ws + 4);
    u16*   nf  = (u16*)(ws + NF_OFF);
    float* P   = (float*)(ws + P_OFF);

    hipMemsetAsync(ws, 0, 256, stream);
    stats_kernel<<<NROWS, 256, 0, stream>>>(wgt, mask, nf, cnt);
    gemm_kernel<<<NT128 * KS, 256, 0, stream>>>(nf, cnt, P);
    reduce_kernel<<<NT128 * 4, 256, 0, stream>>>(P, cnt, sq);
    final_kernel<<<1, 1, 0, stream>>>(cnt, sq, out);
}